// Round 19
// baseline (313.341 us; speedup 1.0000x reference)
//
#include <hip/hip_runtime.h>
#include <hip/hip_bf16.h>
#include <stdint.h>

typedef float  f32x4  __attribute__((ext_vector_type(4)));
typedef float  f32x16 __attribute__((ext_vector_type(16)));
typedef short  s16x8  __attribute__((ext_vector_type(8)));

#define D_MODEL 2048
#define NHEADS  16
#define DK      128
#define BATCH   2
#define SEQ     2048
#define MROWS   (BATCH*SEQ)   // 4096

__device__ __forceinline__ unsigned short f2bf(float f) {
  union { float f; unsigned int u; } v; v.f = f;
  unsigned int r = v.u + 0x7FFFu + ((v.u >> 16) & 1u);
  return (unsigned short)(r >> 16);
}

__device__ __forceinline__ unsigned int packbf_c(float lo, float hi) {
  __hip_bfloat16 l = __float2bfloat16(lo);
  __hip_bfloat16 h = __float2bfloat16(hi);
  unsigned short lu, hu;
  __builtin_memcpy(&lu, &l, 2);
  __builtin_memcpy(&hu, &h, 2);
  return (unsigned int)lu | ((unsigned int)hu << 16);
}

__device__ __forceinline__ void async16(const void* g, void* l) {
  __builtin_amdgcn_global_load_lds(
      (const __attribute__((address_space(1))) unsigned int*)g,
      (__attribute__((address_space(3))) unsigned int*)l,
      16, 0, 0);
}

// ---------------- fused prologue: fp32->bf16 q/k/v convert + weight transpose ----------------
__global__ __launch_bounds__(256) void prep_kernel(const float* __restrict__ q,
                                                   const float* __restrict__ k,
                                                   const float* __restrict__ v,
                                                   const float* __restrict__ Wq,
                                                   const float* __restrict__ Wk,
                                                   const float* __restrict__ Wv,
                                                   const float* __restrict__ Wo,
                                                   unsigned short* __restrict__ qb,
                                                   unsigned short* __restrict__ kb,
                                                   unsigned short* __restrict__ vb,
                                                   unsigned short* __restrict__ WT) {
  const int t = threadIdx.x;
  if (blockIdx.x < 12288) {
    int bz = blockIdx.x / 4096;                 // tensor select
    int bx = blockIdx.x - bz * 4096;
    const float* s = (bz == 0) ? q : (bz == 1) ? k : v;
    unsigned short* d = (bz == 0) ? qb : (bz == 1) ? kb : vb;
    int i = bx * 256 + t;
    const float4* s4 = (const float4*)s;
    float4 a = s4[2*i];
    float4 b = s4[2*i+1];
    s16x8 o;
    o[0] = (short)f2bf(a.x); o[1] = (short)f2bf(a.y);
    o[2] = (short)f2bf(a.z); o[3] = (short)f2bf(a.w);
    o[4] = (short)f2bf(b.x); o[5] = (short)f2bf(b.y);
    o[6] = (short)f2bf(b.z); o[7] = (short)f2bf(b.w);
    *(s16x8*)(d + 8*(size_t)i) = o;
  } else {
    int lin = blockIdx.x - 12288;               // 0..16383
    int z   = lin >> 12;                        // weight select
    int rem = lin & 4095;
    int bx  = rem & 63, by = rem >> 6;
    const float* W = (z == 0) ? Wq : (z == 1) ? Wk : (z == 2) ? Wv : Wo;
    unsigned short* Wt = WT + (size_t)z * D_MODEL * D_MODEL;
    __shared__ float tl[32][33];
    int x = t & 31, y = t >> 5;                 // 32 x 8
    int n0 = bx * 32, k0 = by * 32;
    #pragma unroll
    for (int j = 0; j < 32; j += 8)
      tl[y + j][x] = W[(size_t)(k0 + y + j) * D_MODEL + n0 + x];
    __syncthreads();
    #pragma unroll
    for (int j = 0; j < 32; j += 8)
      Wt[(size_t)(n0 + y + j) * D_MODEL + k0 + x] = f2bf(tl[x][y + j]);
  }
}

// ---------------- GEMM, BM=256 BN=128 BK=64, 8 waves, 3-deep counted-vmcnt pipeline ----------------
// Measured best: ~116-118 us, 0 bank conflicts. mode 0: fp32 [M][N]+bias.
// mode 1: bf16 head-split [B,H,S,dk]. mode 2: bf16 head-split TRANSPOSED [B,H,dk,S].
__device__ __forceinline__ void gemm3b_core(const unsigned short* __restrict__ A,
                                            const unsigned short* __restrict__ Bt,
                                            const float* __restrict__ bias,
                                            void* __restrict__ Cout,
                                            int N, int K, int mode, float scale,
                                            int m0, int n0, char* lds) {
  const int t  = threadIdx.x;
  const int l  = t & 63, w = t >> 6;
  const int wm = w >> 1, wn = w & 1;          // 4M x 2N waves; per-wave 64x64 output
  const int lr = l & 15, lg = l >> 4;

  auto STAGE = [&](int slot, int kt) {
    char* Ad = lds + slot*49152;              // A: 256x64 bf16 = 32KB
    char* Bd = lds + slot*49152 + 32768;      // B: 128x64 bf16 = 16KB
    #pragma unroll
    for (int i = 0; i < 4; ++i) {             // A: 2048 chunks of 16B, 4/thread
      int c = t + 512*i;
      int row = c >> 3, crs = (c & 7) ^ (row & 7);
      async16(A + (size_t)(m0 + row)*K + kt*64 + crs*8, Ad + c*16);
    }
    #pragma unroll
    for (int i = 0; i < 2; ++i) {             // B: 1024 chunks, 2/thread
      int c = t + 512*i;
      int row = c >> 3, crs = (c & 7) ^ (row & 7);
      async16(Bt + (size_t)(n0 + row)*K + kt*64 + crs*8, Bd + c*16);
    }
  };

  const int NT = K >> 6;                      // 32 K-tiles
  STAGE(0, 0);
  STAGE(1, 1);
  asm volatile("s_waitcnt vmcnt(6)" ::: "memory");   // tile 0's 6 loads landed
  __builtin_amdgcn_s_barrier();

  f32x4 acc[4][4] = {};

  for (int kt = 0; kt < NT; ++kt) {
    if (kt + 2 < NT) STAGE((kt + 2) % 3, kt + 2);    // issue first; lands 2 tiles from now
    const char* Ac = lds + (kt % 3)*49152;
    const char* Bc = lds + (kt % 3)*49152 + 32768;

    #pragma unroll
    for (int ks = 0; ks < 2; ++ks) {
      const int cb = ks*64 + lg*16;          // byte col within 128B row
      s16x8 af[4], bf[4];
      #pragma unroll
      for (int mf = 0; mf < 4; ++mf) {
        int row = wm*64 + mf*16 + lr;        // 0..255
        af[mf] = *(const s16x8*)(Ac + row*128 + (cb ^ ((row & 7) << 4)));
      }
      #pragma unroll
      for (int nf = 0; nf < 4; ++nf) {
        int row = wn*64 + nf*16 + lr;        // 0..127
        bf[nf] = *(const s16x8*)(Bc + row*128 + (cb ^ ((row & 7) << 4)));
      }
      __builtin_amdgcn_s_setprio(1);
      #pragma unroll
      for (int mf = 0; mf < 4; ++mf)
        #pragma unroll
        for (int nf = 0; nf < 4; ++nf)
          acc[mf][nf] = __builtin_amdgcn_mfma_f32_16x16x32_bf16(af[mf], bf[nf], acc[mf][nf], 0, 0, 0);
      __builtin_amdgcn_s_setprio(0);
    }

    if (kt + 1 < NT) {
      if (kt + 2 < NT) asm volatile("s_waitcnt vmcnt(6)" ::: "memory");  // t+1 landed; t+2 flies on
      else             asm volatile("s_waitcnt vmcnt(0)" ::: "memory");  // tail drain
      __builtin_amdgcn_s_barrier();
    }
  }

  if (mode == 0) {
    float* C = (float*)Cout;
    #pragma unroll
    for (int nf = 0; nf < 4; ++nf) {
      int col = n0 + wn*64 + nf*16 + lr;
      float bv = bias[col];
      #pragma unroll
      for (int mf = 0; mf < 4; ++mf) {
        int rowb = m0 + wm*64 + mf*16 + lg*4;
        #pragma unroll
        for (int r = 0; r < 4; ++r)
          C[(size_t)(rowb + r)*N + col] = (acc[mf][nf][r] + bv) * scale;
      }
    }
  } else if (mode == 1) {
    unsigned short* C = (unsigned short*)Cout;
    #pragma unroll
    for (int nf = 0; nf < 4; ++nf) {
      int col = n0 + wn*64 + nf*16 + lr;
      float bv = bias[col];
      int h = col >> 7, dkk = col & 127;
      #pragma unroll
      for (int mf = 0; mf < 4; ++mf) {
        int rowb = m0 + wm*64 + mf*16 + lg*4;
        #pragma unroll
        for (int r = 0; r < 4; ++r) {
          int row = rowb + r;
          int b = row >> 11, s = row & 2047;
          C[((size_t)((b*NHEADS + h)*SEQ + s))*DK + dkk] = f2bf((acc[mf][nf][r] + bv) * scale);
        }
      }
    }
  } else {                                    // mode 2: V^T head-split [B,H,dk,S]
    unsigned short* C = (unsigned short*)Cout;
    #pragma unroll
    for (int nf = 0; nf < 4; ++nf) {
      int col = n0 + wn*64 + nf*16 + lr;
      float bv = bias[col];
      int h = col >> 7, dkk = col & 127;
      #pragma unroll
      for (int mf = 0; mf < 4; ++mf) {
        int rowb = m0 + wm*64 + mf*16 + lg*4;
        #pragma unroll
        for (int r = 0; r < 4; ++r) {
          int row = rowb + r;
          int b = row >> 11, s = row & 2047;
          C[((size_t)((b*NHEADS + h)*DK + dkk))*SEQ + s] = f2bf((acc[mf][nf][r] + bv) * scale);
        }
      }
    }
  }
}

// T1 chunked XCD swizzle over the 16x16 block grid (256 blocks/z, %8==0, bijective)
__device__ __forceinline__ void swz_mn(int& m0, int& n0) {
  int lin = blockIdx.y * 16 + blockIdx.x;     // 0..255
  int xcd = lin & 7;
  int pos = lin >> 3;                         // 0..31
  n0 = (xcd*2 + (pos & 1)) * 128;
  m0 = (pos >> 1) * 256;
}

// fused Q/K/V projections (Q,K: mode 1; V: mode 2 transposed)
__global__ __launch_bounds__(512) void gemm256_qkv(const unsigned short* __restrict__ qb,
                                                   const unsigned short* __restrict__ kb,
                                                   const unsigned short* __restrict__ vb,
                                                   const unsigned short* __restrict__ WT,
                                                   const float* __restrict__ bq,
                                                   const float* __restrict__ bk,
                                                   const float* __restrict__ bv,
                                                   unsigned short* __restrict__ Hout,
                                                   float qscale) {
  __shared__ char lds[147456];   // 144KB = 3 x 48KB slots
  const int z = blockIdx.z;
  const unsigned short* A = (z == 0) ? qb : (z == 1) ? kb : vb;
  const float* bias       = (z == 0) ? bq : (z == 1) ? bk : bv;
  const float scale       = (z == 0) ? qscale : 1.0f;
  const int   mode        = (z == 2) ? 2 : 1;
  const unsigned short* Bt = WT + (size_t)z * D_MODEL * D_MODEL;
  unsigned short* Cout     = Hout + (size_t)z * MROWS * D_MODEL;
  int m0, n0; swz_mn(m0, n0);
  gemm3b_core(A, Bt, bias, Cout, D_MODEL, D_MODEL, mode, scale, m0, n0, lds);
}

// out-projection (mode 0, fp32 out)
__global__ __launch_bounds__(512) void gemm256_out(const unsigned short* __restrict__ A,
                                                   const unsigned short* __restrict__ Bt,
                                                   const float* __restrict__ bias,
                                                   float* __restrict__ Cout) {
  __shared__ char lds[147456];   // 144KB
  int m0, n0; swz_mn(m0, n0);
  gemm3b_core(A, Bt, bias, Cout, D_MODEL, D_MODEL, 0, 1.0f, m0, n0, lds);
}

// ---------------- flash attention, swapped-QK^T 32x32, all-gload_lds staging (measured best) ----------------
// V pre-transposed in global ([B,H,dk,S]); staged like K: gload_lds linear dest + inverse-swizzled
// source; Kl single (16KB), Vt double-buffered (2x16KB). Per tile: __syncthreads [drains K(t),V(t)]
// -> QK^T -> __syncthreads [Kl dead] -> stage K(t+1)+V(t+1,buf^1) -> softmax+pack+PV.
// r19 polish: v_max3 chains for the 32-value max tree; cross-lane pmax shfl only when rescaling.
__global__ __launch_bounds__(256, 2) void attn_kernel(const unsigned short* __restrict__ Q,
                                                      const unsigned short* __restrict__ K,
                                                      const unsigned short* __restrict__ Vt_g,
                                                      unsigned short* __restrict__ O) {
  __shared__ char lds[64*256 + 2*16384];           // Kl 16KB + Vt[2] 32KB (reused as O-bounce)
  unsigned short* Kl = (unsigned short*)lds;       // [64 kv][128 dk] bf16, XOR-swizzled rows (256B)

  const int t  = threadIdx.x;
  const int l  = t & 63, w = t >> 6;
  const int q_ = l & 31, hi = l >> 5;
  const int bh = blockIdx.y;
  const int b  = bh >> 4, h = bh & 15;
  const int q0 = blockIdx.x * 128;

  const unsigned short* Qp = Q    + (size_t)bh * SEQ * DK;
  const unsigned short* Kp = K    + (size_t)bh * SEQ * DK;
  const unsigned short* Vp = Vt_g + (size_t)bh * DK * SEQ;   // rows = dv, cols = s

  const int qrow = q0 + w*32 + q_;
  s16x8 aq[8];
  #pragma unroll
  for (int kk = 0; kk < 8; ++kk)
    aq[kk] = *(const s16x8*)(Qp + (size_t)qrow*DK + kk*16 + hi*8);

  f32x16 accO[4] = {};                 // C[dv][q = q_]
  float m = -INFINITY, L = 0.f;

  const int NT = SEQ/64;

  auto stageK = [&](int kv0) {
    #pragma unroll
    for (int i = 0; i < 4; ++i) {
      int c   = t + 256*i;                 // 1024 chunks; 16/row of 256B
      int row = c >> 4;
      int sb  = ((c & 15) << 4) ^ ((row & 15) << 4);
      async16((const char*)(Kp + (size_t)(kv0 + row)*DK) + sb, (char*)Kl + c*16);
    }
  };
  auto stageV = [&](int kv0, int buf) {
    char* Vd = lds + 16384 + buf*16384;
    #pragma unroll
    for (int i = 0; i < 4; ++i) {
      int c   = t + 256*i;                 // 1024 chunks; 8/row of 128B
      int row = c >> 3;                    // dv 0..127
      int sb  = ((c & 7) << 4) ^ ((row & 7) << 4);
      async16((const char*)(Vp + (size_t)row*SEQ + kv0) + sb, Vd + c*16);
    }
  };

  stageK(0);
  stageV(0, 0);
  asm volatile("" ::: "memory");

  for (int tt = 0; tt < NT; ++tt) {
    __syncthreads();                       // drains K(t)+V(t) loads; all staged & visible

    // ---- S^T[kv][q] = K Q^T (log2-domain scores) ----
    f32x16 S0 = {}, S1 = {};
    __builtin_amdgcn_s_setprio(1);
    #pragma unroll
    for (int t2 = 0; t2 < 2; ++t2) {
      int krow = t2*32 + q_;
      const char* kb = (const char*)Kl + krow*256;
      int swz = (krow & 15) << 4;
      #pragma unroll
      for (int kk = 0; kk < 8; ++kk) {
        s16x8 kf = *(const s16x8*)(kb + ((kk*32 + hi*16) ^ swz));
        if (t2 == 0) S0 = __builtin_amdgcn_mfma_f32_32x32x16_bf16(kf, aq[kk], S0, 0, 0, 0);
        else         S1 = __builtin_amdgcn_mfma_f32_32x32x16_bf16(kf, aq[kk], S1, 0, 0, 0);
      }
    }
    __builtin_amdgcn_s_setprio(0);
    __syncthreads();                       // Kl dead; no vmem outstanding here

    if (tt + 1 < NT) {
      stageK((tt + 1) * 64);
      stageV((tt + 1) * 64, (tt + 1) & 1); // buf^1: its last reader was tile t-1's PV
      asm volatile("" ::: "memory");
    }

    // ---- in-register online softmax (exp2 domain, defer-max THR=11) ----
    // 4 linear triple-chains (fuse to v_max3_f32), combined at the end.
    float c0 = fmaxf(fmaxf(S0[0],  S0[1]),  S0[2]);
    float c1 = fmaxf(fmaxf(S0[8],  S0[9]),  S0[10]);
    float c2 = fmaxf(fmaxf(S1[0],  S1[1]),  S1[2]);
    float c3 = fmaxf(fmaxf(S1[8],  S1[9]),  S1[10]);
    c0 = fmaxf(fmaxf(c0, S0[3]),  S0[4]);
    c1 = fmaxf(fmaxf(c1, S0[11]), S0[12]);
    c2 = fmaxf(fmaxf(c2, S1[3]),  S1[4]);
    c3 = fmaxf(fmaxf(c3, S1[11]), S1[12]);
    c0 = fmaxf(fmaxf(c0, S0[5]),  S0[6]);
    c1 = fmaxf(fmaxf(c1, S0[13]), S0[14]);
    c2 = fmaxf(fmaxf(c2, S1[5]),  S1[6]);
    c3 = fmaxf(fmaxf(c3, S1[13]), S1[14]);
    c0 = fmaxf(fmaxf(c0, S0[7]),  S0[15]);
    c1 = fmaxf(fmaxf(c1, S1[7]),  S1[15]);
    float pmax_loc = fmaxf(fmaxf(fmaxf(c0, c1), c2), c3);

    if (!__all(pmax_loc <= m + 11.0f)) {   // same decision as shuffled variant (all-reduce)
      float pmax = fmaxf(pmax_loc, __shfl_xor(pmax_loc, 32, 64));
      float mnew = fmaxf(m, pmax);
      float corr = exp2f(m - mnew);
      m = mnew;
      L *= corr;
      #pragma unroll
      for (int sub = 0; sub < 4; ++sub)
        #pragma unroll
        for (int r = 0; r < 16; ++r) accO[sub][r] *= corr;
    }

    float rs0 = 0.f, rs1 = 0.f, rs2 = 0.f, rs3 = 0.f;
    #pragma unroll
    for (int r = 0; r < 4; ++r) {
      float a0 = exp2f(S0[r]    - m); S0[r]    = a0; rs0 += a0;
      float a1 = exp2f(S0[r+4]  - m); S0[r+4]  = a1; rs1 += a1;
      float a2 = exp2f(S0[r+8]  - m); S0[r+8]  = a2; rs2 += a2;
      float a3 = exp2f(S0[r+12] - m); S0[r+12] = a3; rs3 += a3;
      float b0 = exp2f(S1[r]    - m); S1[r]    = b0; rs0 += b0;
      float b1 = exp2f(S1[r+4]  - m); S1[r+4]  = b1; rs1 += b1;
      float b2 = exp2f(S1[r+8]  - m); S1[r+8]  = b2; rs2 += b2;
      float b3 = exp2f(S1[r+12] - m); S1[r+12] = b3; rs3 += b3;
    }
    float rs = (rs0 + rs1) + (rs2 + rs3);
    rs += __shfl_xor(rs, 32, 64);
    L += rs;

    // ---- P -> bf16 B-fragments via shfl_xor(32) + select ----
    s16x8 PB[4];
    #pragma unroll
    for (int t2 = 0; t2 < 2; ++t2) {
      #pragma unroll
      for (int half = 0; half < 2; ++half) {
        int bse = half*8;
        unsigned int pkA01, pkA23, pkB01, pkB23;
        if (t2 == 0) {
          pkA01 = packbf_c(S0[bse+0], S0[bse+1]);
          pkA23 = packbf_c(S0[bse+2], S0[bse+3]);
          pkB01 = packbf_c(S0[bse+4], S0[bse+5]);
          pkB23 = packbf_c(S0[bse+6], S0[bse+7]);
        } else {
          pkA01 = packbf_c(S1[bse+0], S1[bse+1]);
          pkA23 = packbf_c(S1[bse+2], S1[bse+3]);
          pkB01 = packbf_c(S1[bse+4], S1[bse+5]);
          pkB23 = packbf_c(S1[bse+6], S1[bse+7]);
        }
        unsigned int xA01 = __shfl_xor(pkA01, 32, 64);
        unsigned int xA23 = __shfl_xor(pkA23, 32, 64);
        unsigned int xB01 = __shfl_xor(pkB01, 32, 64);
        unsigned int xB23 = __shfl_xor(pkB23, 32, 64);
        union { unsigned int u[4]; s16x8 v; } f;
        f.u[0] = hi ? xB01 : pkA01;
        f.u[1] = hi ? xB23 : pkA23;
        f.u[2] = hi ? pkB01 : xA01;
        f.u[3] = hi ? pkB23 : xA23;
        PB[t2*2 + half] = f.v;
      }
    }

    // ---- O^T += V^T P^T : C[dv][q]; V^T frags from swizzled Vt[buf] ----
    const char* Vc = lds + 16384 + (tt & 1)*16384;
    __builtin_amdgcn_s_setprio(1);
    #pragma unroll
    for (int sub = 0; sub < 4; ++sub) {
      int row = sub*32 + q_;                // dv
      const char* vb2 = Vc + row*128;
      int swz = (row & 7) << 4;
      #pragma unroll
      for (int kk = 0; kk < 4; ++kk) {
        s16x8 vf = *(const s16x8*)(vb2 + ((kk*32 + hi*16) ^ swz));
        accO[sub] = __builtin_amdgcn_mfma_f32_32x32x16_bf16(vf, PB[kk], accO[sub], 0, 0, 0);
      }
    }
    __builtin_amdgcn_s_setprio(0);
  }

  // ---- epilogue: per-wave LDS bounce to coalesce [q][dv] stores ----
  __syncthreads();
  unsigned short* Ob = (unsigned short*)lds + (size_t)w*4096;   // 8KB/wave
  float inv = 1.0f / L;
  #pragma unroll
  for (int sub = 0; sub < 4; ++sub)
    #pragma unroll
    for (int j = 0; j < 8; ++j) {
      unsigned int pw = packbf_c(accO[sub][2*j]*inv, accO[sub][2*j+1]*inv);
      int dv = sub*32 + (j&1)*2 + ((j>>1)*8) + 4*hi;
      *(unsigned int*)((char*)Ob + q_*256 + ((dv*2) ^ ((q_ & 15) << 4))) = pw;
    }
  asm volatile("s_waitcnt lgkmcnt(0)" ::: "memory");
  size_t gbase = ((size_t)(b*SEQ + q0 + w*32 + q_))*D_MODEL + h*DK;
  #pragma unroll
  for (int p = 0; p < 8; ++p) {
    int chunk = hi + 2*p;
    s16x8 ov = *(const s16x8*)((char*)Ob + q_*256 + ((chunk*16) ^ ((q_ & 15) << 4)));
    *(s16x8*)(O + gbase + chunk*8) = ov;
  }
}

extern "C" void kernel_launch(void* const* d_in, const int* in_sizes, int n_in,
                              void* d_out, int out_size, void* d_ws, size_t ws_size,
                              hipStream_t stream) {
  const float* q  = (const float*)d_in[0];
  const float* k  = (const float*)d_in[1];
  const float* v  = (const float*)d_in[2];
  const float* Wq = (const float*)d_in[3];
  const float* bq = (const float*)d_in[4];
  const float* Wk = (const float*)d_in[5];
  const float* bk = (const float*)d_in[6];
  const float* Wv = (const float*)d_in[7];
  const float* bv = (const float*)d_in[8];
  const float* Wo = (const float*)d_in[9];
  const float* bo = (const float*)d_in[10];
  float* out = (float*)d_out;

  char* ws = (char*)d_ws;
  const size_t SZT = (size_t)MROWS * D_MODEL * 2;
  const size_t SZW = (size_t)D_MODEL * D_MODEL * 2;

  unsigned short* qb  = (unsigned short*)(ws);
  unsigned short* kb  = (unsigned short*)(ws + SZT);
  unsigned short* vb  = (unsigned short*)(ws + 2*SZT);
  unsigned short* WqT = (unsigned short*)(ws + 3*SZT);            // [4][2048][2048] contiguous
  unsigned short* WoT = (unsigned short*)(ws + 3*SZT + 3*SZW);
  unsigned short* Qh  = (unsigned short*)(ws + 3*SZT + 4*SZW);    // [3] tensors contiguous
  unsigned short* Kh  = (unsigned short*)(ws + 4*SZT + 4*SZW);
  unsigned short* Vh  = (unsigned short*)(ws + 5*SZT + 4*SZW);    // V^T layout [B,H,dk,S]
  unsigned short* Oc  = qb;   // qb dead after Q projection

  prep_kernel<<<dim3(12288 + 16384), 256, 0, stream>>>(q, k, v, Wq, Wk, Wv, Wo, qb, kb, vb, WqT);

  // 1/sqrt(128) * log2(e): scores computed directly in exp2 domain
  const float qscale = 0.1275174308f;
  gemm256_qkv<<<dim3(16, 16, 3), 512, 0, stream>>>(qb, kb, vb, WqT, bq, bk, bv, Qh, qscale);

  attn_kernel<<<dim3(SEQ/128, BATCH*NHEADS), 256, 0, stream>>>(Qh, Kh, Vh, Oc);

  gemm256_out<<<dim3(16, 16), 512, 0, stream>>>(Oc, WoT, bo, out);
}

// Round 20
// 302.330 us; speedup vs baseline: 1.0364x; 1.0364x over previous
//
#include <hip/hip_runtime.h>
#include <hip/hip_bf16.h>
#include <stdint.h>

typedef float  f32x4  __attribute__((ext_vector_type(4)));
typedef float  f32x16 __attribute__((ext_vector_type(16)));
typedef short  s16x8  __attribute__((ext_vector_type(8)));

#define D_MODEL 2048
#define NHEADS  16
#define DK      128
#define BATCH   2
#define SEQ     2048
#define MROWS   (BATCH*SEQ)   // 4096

__device__ __forceinline__ unsigned short f2bf(float f) {
  union { float f; unsigned int u; } v; v.f = f;
  unsigned int r = v.u + 0x7FFFu + ((v.u >> 16) & 1u);
  return (unsigned short)(r >> 16);
}

__device__ __forceinline__ unsigned int packbf_c(float lo, float hi) {
  __hip_bfloat16 l = __float2bfloat16(lo);
  __hip_bfloat16 h = __float2bfloat16(hi);
  unsigned short lu, hu;
  __builtin_memcpy(&lu, &l, 2);
  __builtin_memcpy(&hu, &h, 2);
  return (unsigned int)lu | ((unsigned int)hu << 16);
}

__device__ __forceinline__ void async16(const void* g, void* l) {
  __builtin_amdgcn_global_load_lds(
      (const __attribute__((address_space(1))) unsigned int*)g,
      (__attribute__((address_space(3))) unsigned int*)l,
      16, 0, 0);
}

// ---------------- fused prologue: fp32->bf16 q/k/v convert + weight transpose ----------------
__global__ __launch_bounds__(256) void prep_kernel(const float* __restrict__ q,
                                                   const float* __restrict__ k,
                                                   const float* __restrict__ v,
                                                   const float* __restrict__ Wq,
                                                   const float* __restrict__ Wk,
                                                   const float* __restrict__ Wv,
                                                   const float* __restrict__ Wo,
                                                   unsigned short* __restrict__ qb,
                                                   unsigned short* __restrict__ kb,
                                                   unsigned short* __restrict__ vb,
                                                   unsigned short* __restrict__ WT) {
  const int t = threadIdx.x;
  if (blockIdx.x < 12288) {
    int bz = blockIdx.x / 4096;                 // tensor select
    int bx = blockIdx.x - bz * 4096;
    const float* s = (bz == 0) ? q : (bz == 1) ? k : v;
    unsigned short* d = (bz == 0) ? qb : (bz == 1) ? kb : vb;
    int i = bx * 256 + t;
    const float4* s4 = (const float4*)s;
    float4 a = s4[2*i];
    float4 b = s4[2*i+1];
    s16x8 o;
    o[0] = (short)f2bf(a.x); o[1] = (short)f2bf(a.y);
    o[2] = (short)f2bf(a.z); o[3] = (short)f2bf(a.w);
    o[4] = (short)f2bf(b.x); o[5] = (short)f2bf(b.y);
    o[6] = (short)f2bf(b.z); o[7] = (short)f2bf(b.w);
    *(s16x8*)(d + 8*(size_t)i) = o;
  } else {
    int lin = blockIdx.x - 12288;               // 0..16383
    int z   = lin >> 12;                        // weight select
    int rem = lin & 4095;
    int bx  = rem & 63, by = rem >> 6;
    const float* W = (z == 0) ? Wq : (z == 1) ? Wk : (z == 2) ? Wv : Wo;
    unsigned short* Wt = WT + (size_t)z * D_MODEL * D_MODEL;
    __shared__ float tl[32][33];
    int x = t & 31, y = t >> 5;                 // 32 x 8
    int n0 = bx * 32, k0 = by * 32;
    #pragma unroll
    for (int j = 0; j < 32; j += 8)
      tl[y + j][x] = W[(size_t)(k0 + y + j) * D_MODEL + n0 + x];
    __syncthreads();
    #pragma unroll
    for (int j = 0; j < 32; j += 8)
      Wt[(size_t)(n0 + y + j) * D_MODEL + k0 + x] = f2bf(tl[x][y + j]);
  }
}

// ---------------- GEMM, BM=256 BN=128 BK=64, 8 waves, 3-deep counted-vmcnt pipeline ----------------
// Measured best: ~116-118 us, 0 bank conflicts. mode 0: fp32 [M][N]+bias.
// mode 1: bf16 head-split [B,H,S,dk]. mode 2: bf16 head-split TRANSPOSED [B,H,dk,S].
__device__ __forceinline__ void gemm3b_core(const unsigned short* __restrict__ A,
                                            const unsigned short* __restrict__ Bt,
                                            const float* __restrict__ bias,
                                            void* __restrict__ Cout,
                                            int N, int K, int mode, float scale,
                                            int m0, int n0, char* lds) {
  const int t  = threadIdx.x;
  const int l  = t & 63, w = t >> 6;
  const int wm = w >> 1, wn = w & 1;          // 4M x 2N waves; per-wave 64x64 output
  const int lr = l & 15, lg = l >> 4;

  auto STAGE = [&](int slot, int kt) {
    char* Ad = lds + slot*49152;              // A: 256x64 bf16 = 32KB
    char* Bd = lds + slot*49152 + 32768;      // B: 128x64 bf16 = 16KB
    #pragma unroll
    for (int i = 0; i < 4; ++i) {             // A: 2048 chunks of 16B, 4/thread
      int c = t + 512*i;
      int row = c >> 3, crs = (c & 7) ^ (row & 7);
      async16(A + (size_t)(m0 + row)*K + kt*64 + crs*8, Ad + c*16);
    }
    #pragma unroll
    for (int i = 0; i < 2; ++i) {             // B: 1024 chunks, 2/thread
      int c = t + 512*i;
      int row = c >> 3, crs = (c & 7) ^ (row & 7);
      async16(Bt + (size_t)(n0 + row)*K + kt*64 + crs*8, Bd + c*16);
    }
  };

  const int NT = K >> 6;                      // 32 K-tiles
  STAGE(0, 0);
  STAGE(1, 1);
  asm volatile("s_waitcnt vmcnt(6)" ::: "memory");   // tile 0's 6 loads landed
  __builtin_amdgcn_s_barrier();

  f32x4 acc[4][4] = {};

  for (int kt = 0; kt < NT; ++kt) {
    if (kt + 2 < NT) STAGE((kt + 2) % 3, kt + 2);    // issue first; lands 2 tiles from now
    const char* Ac = lds + (kt % 3)*49152;
    const char* Bc = lds + (kt % 3)*49152 + 32768;

    #pragma unroll
    for (int ks = 0; ks < 2; ++ks) {
      const int cb = ks*64 + lg*16;          // byte col within 128B row
      s16x8 af[4], bf[4];
      #pragma unroll
      for (int mf = 0; mf < 4; ++mf) {
        int row = wm*64 + mf*16 + lr;        // 0..255
        af[mf] = *(const s16x8*)(Ac + row*128 + (cb ^ ((row & 7) << 4)));
      }
      #pragma unroll
      for (int nf = 0; nf < 4; ++nf) {
        int row = wn*64 + nf*16 + lr;        // 0..127
        bf[nf] = *(const s16x8*)(Bc + row*128 + (cb ^ ((row & 7) << 4)));
      }
      __builtin_amdgcn_s_setprio(1);
      #pragma unroll
      for (int mf = 0; mf < 4; ++mf)
        #pragma unroll
        for (int nf = 0; nf < 4; ++nf)
          acc[mf][nf] = __builtin_amdgcn_mfma_f32_16x16x32_bf16(af[mf], bf[nf], acc[mf][nf], 0, 0, 0);
      __builtin_amdgcn_s_setprio(0);
    }

    if (kt + 1 < NT) {
      if (kt + 2 < NT) asm volatile("s_waitcnt vmcnt(6)" ::: "memory");  // t+1 landed; t+2 flies on
      else             asm volatile("s_waitcnt vmcnt(0)" ::: "memory");  // tail drain
      __builtin_amdgcn_s_barrier();
    }
  }

  if (mode == 0) {
    float* C = (float*)Cout;
    #pragma unroll
    for (int nf = 0; nf < 4; ++nf) {
      int col = n0 + wn*64 + nf*16 + lr;
      float bv = bias[col];
      #pragma unroll
      for (int mf = 0; mf < 4; ++mf) {
        int rowb = m0 + wm*64 + mf*16 + lg*4;
        #pragma unroll
        for (int r = 0; r < 4; ++r)
          C[(size_t)(rowb + r)*N + col] = (acc[mf][nf][r] + bv) * scale;
      }
    }
  } else if (mode == 1) {
    unsigned short* C = (unsigned short*)Cout;
    #pragma unroll
    for (int nf = 0; nf < 4; ++nf) {
      int col = n0 + wn*64 + nf*16 + lr;
      float bv = bias[col];
      int h = col >> 7, dkk = col & 127;
      #pragma unroll
      for (int mf = 0; mf < 4; ++mf) {
        int rowb = m0 + wm*64 + mf*16 + lg*4;
        #pragma unroll
        for (int r = 0; r < 4; ++r) {
          int row = rowb + r;
          int b = row >> 11, s = row & 2047;
          C[((size_t)((b*NHEADS + h)*SEQ + s))*DK + dkk] = f2bf((acc[mf][nf][r] + bv) * scale);
        }
      }
    }
  } else {                                    // mode 2: V^T head-split [B,H,dk,S]
    unsigned short* C = (unsigned short*)Cout;
    #pragma unroll
    for (int nf = 0; nf < 4; ++nf) {
      int col = n0 + wn*64 + nf*16 + lr;
      float bv = bias[col];
      int h = col >> 7, dkk = col & 127;
      #pragma unroll
      for (int mf = 0; mf < 4; ++mf) {
        int rowb = m0 + wm*64 + mf*16 + lg*4;
        #pragma unroll
        for (int r = 0; r < 4; ++r) {
          int row = rowb + r;
          int b = row >> 11, s = row & 2047;
          C[((size_t)((b*NHEADS + h)*DK + dkk))*SEQ + s] = f2bf((acc[mf][nf][r] + bv) * scale);
        }
      }
    }
  }
}

// T1 chunked XCD swizzle over the 16x16 block grid (256 blocks/z, %8==0, bijective)
__device__ __forceinline__ void swz_mn(int& m0, int& n0) {
  int lin = blockIdx.y * 16 + blockIdx.x;     // 0..255
  int xcd = lin & 7;
  int pos = lin >> 3;                         // 0..31
  n0 = (xcd*2 + (pos & 1)) * 128;
  m0 = (pos >> 1) * 256;
}

// fused Q/K/V projections (Q,K: mode 1; V: mode 2 transposed)
__global__ __launch_bounds__(512) void gemm256_qkv(const unsigned short* __restrict__ qb,
                                                   const unsigned short* __restrict__ kb,
                                                   const unsigned short* __restrict__ vb,
                                                   const unsigned short* __restrict__ WT,
                                                   const float* __restrict__ bq,
                                                   const float* __restrict__ bk,
                                                   const float* __restrict__ bv,
                                                   unsigned short* __restrict__ Hout,
                                                   float qscale) {
  __shared__ char lds[147456];   // 144KB = 3 x 48KB slots
  const int z = blockIdx.z;
  const unsigned short* A = (z == 0) ? qb : (z == 1) ? kb : vb;
  const float* bias       = (z == 0) ? bq : (z == 1) ? bk : bv;
  const float scale       = (z == 0) ? qscale : 1.0f;
  const int   mode        = (z == 2) ? 2 : 1;
  const unsigned short* Bt = WT + (size_t)z * D_MODEL * D_MODEL;
  unsigned short* Cout     = Hout + (size_t)z * MROWS * D_MODEL;
  int m0, n0; swz_mn(m0, n0);
  gemm3b_core(A, Bt, bias, Cout, D_MODEL, D_MODEL, mode, scale, m0, n0, lds);
}

// out-projection (mode 0, fp32 out)
__global__ __launch_bounds__(512) void gemm256_out(const unsigned short* __restrict__ A,
                                                   const unsigned short* __restrict__ Bt,
                                                   const float* __restrict__ bias,
                                                   float* __restrict__ Cout) {
  __shared__ char lds[147456];   // 144KB
  int m0, n0; swz_mn(m0, n0);
  gemm3b_core(A, Bt, bias, Cout, D_MODEL, D_MODEL, 0, 1.0f, m0, n0, lds);
}

// ---------------- flash attention, swapped-QK^T 32x32, all-gload_lds staging (round-18 best) ----------------
// V pre-transposed in global ([B,H,dk,S]); staged like K: gload_lds linear dest + inverse-swizzled
// source; Kl single (16KB), Vt double-buffered (2x16KB). Per tile: __syncthreads [drains K(t),V(t)]
// -> QK^T -> __syncthreads [Kl dead] -> stage K(t+1)+V(t+1,buf^1) -> softmax+pack+PV.
__global__ __launch_bounds__(256, 2) void attn_kernel(const unsigned short* __restrict__ Q,
                                                      const unsigned short* __restrict__ K,
                                                      const unsigned short* __restrict__ Vt_g,
                                                      unsigned short* __restrict__ O) {
  __shared__ char lds[64*256 + 2*16384];           // Kl 16KB + Vt[2] 32KB (reused as O-bounce)
  unsigned short* Kl = (unsigned short*)lds;       // [64 kv][128 dk] bf16, XOR-swizzled rows (256B)

  const int t  = threadIdx.x;
  const int l  = t & 63, w = t >> 6;
  const int q_ = l & 31, hi = l >> 5;
  const int bh = blockIdx.y;
  const int b  = bh >> 4, h = bh & 15;
  const int q0 = blockIdx.x * 128;

  const unsigned short* Qp = Q    + (size_t)bh * SEQ * DK;
  const unsigned short* Kp = K    + (size_t)bh * SEQ * DK;
  const unsigned short* Vp = Vt_g + (size_t)bh * DK * SEQ;   // rows = dv, cols = s

  const int qrow = q0 + w*32 + q_;
  s16x8 aq[8];
  #pragma unroll
  for (int kk = 0; kk < 8; ++kk)
    aq[kk] = *(const s16x8*)(Qp + (size_t)qrow*DK + kk*16 + hi*8);

  f32x16 accO[4] = {};                 // C[dv][q = q_]
  float m = -INFINITY, L = 0.f;

  const int NT = SEQ/64;

  auto stageK = [&](int kv0) {
    #pragma unroll
    for (int i = 0; i < 4; ++i) {
      int c   = t + 256*i;                 // 1024 chunks; 16/row of 256B
      int row = c >> 4;
      int sb  = ((c & 15) << 4) ^ ((row & 15) << 4);
      async16((const char*)(Kp + (size_t)(kv0 + row)*DK) + sb, (char*)Kl + c*16);
    }
  };
  auto stageV = [&](int kv0, int buf) {
    char* Vd = lds + 16384 + buf*16384;
    #pragma unroll
    for (int i = 0; i < 4; ++i) {
      int c   = t + 256*i;                 // 1024 chunks; 8/row of 128B
      int row = c >> 3;                    // dv 0..127
      int sb  = ((c & 7) << 4) ^ ((row & 7) << 4);
      async16((const char*)(Vp + (size_t)row*SEQ + kv0) + sb, Vd + c*16);
    }
  };

  stageK(0);
  stageV(0, 0);
  asm volatile("" ::: "memory");

  for (int tt = 0; tt < NT; ++tt) {
    __syncthreads();                       // drains K(t)+V(t) loads; all staged & visible

    // ---- S^T[kv][q] = K Q^T (log2-domain scores) ----
    f32x16 S0 = {}, S1 = {};
    __builtin_amdgcn_s_setprio(1);
    #pragma unroll
    for (int t2 = 0; t2 < 2; ++t2) {
      int krow = t2*32 + q_;
      const char* kb = (const char*)Kl + krow*256;
      int swz = (krow & 15) << 4;
      #pragma unroll
      for (int kk = 0; kk < 8; ++kk) {
        s16x8 kf = *(const s16x8*)(kb + ((kk*32 + hi*16) ^ swz));
        if (t2 == 0) S0 = __builtin_amdgcn_mfma_f32_32x32x16_bf16(kf, aq[kk], S0, 0, 0, 0);
        else         S1 = __builtin_amdgcn_mfma_f32_32x32x16_bf16(kf, aq[kk], S1, 0, 0, 0);
      }
    }
    __builtin_amdgcn_s_setprio(0);
    __syncthreads();                       // Kl dead; no vmem outstanding here

    if (tt + 1 < NT) {
      stageK((tt + 1) * 64);
      stageV((tt + 1) * 64, (tt + 1) & 1); // buf^1: its last reader was tile t-1's PV
      asm volatile("" ::: "memory");
    }

    // ---- in-register online softmax (exp2 domain, defer-max THR=11) ----
    f32x16 mx;
    #pragma unroll
    for (int r = 0; r < 16; ++r) mx[r] = fmaxf(S0[r], S1[r]);
    float m8_[8];
    #pragma unroll
    for (int r = 0; r < 8; ++r) m8_[r] = fmaxf(mx[r], mx[r+8]);
    float m4a = fmaxf(m8_[0], m8_[4]), m4b = fmaxf(m8_[1], m8_[5]);
    float m4c = fmaxf(m8_[2], m8_[6]), m4d = fmaxf(m8_[3], m8_[7]);
    float pmax = fmaxf(fmaxf(m4a, m4b), fmaxf(m4c, m4d));
    pmax = fmaxf(pmax, __shfl_xor(pmax, 32, 64));

    if (!__all(pmax <= m + 11.0f)) {
      float mnew = fmaxf(m, pmax);
      float corr = exp2f(m - mnew);
      m = mnew;
      L *= corr;
      #pragma unroll
      for (int sub = 0; sub < 4; ++sub)
        #pragma unroll
        for (int r = 0; r < 16; ++r) accO[sub][r] *= corr;
    }

    float rs0 = 0.f, rs1 = 0.f, rs2 = 0.f, rs3 = 0.f;
    #pragma unroll
    for (int r = 0; r < 4; ++r) {
      float a0 = exp2f(S0[r]    - m); S0[r]    = a0; rs0 += a0;
      float a1 = exp2f(S0[r+4]  - m); S0[r+4]  = a1; rs1 += a1;
      float a2 = exp2f(S0[r+8]  - m); S0[r+8]  = a2; rs2 += a2;
      float a3 = exp2f(S0[r+12] - m); S0[r+12] = a3; rs3 += a3;
      float b0 = exp2f(S1[r]    - m); S1[r]    = b0; rs0 += b0;
      float b1 = exp2f(S1[r+4]  - m); S1[r+4]  = b1; rs1 += b1;
      float b2 = exp2f(S1[r+8]  - m); S1[r+8]  = b2; rs2 += b2;
      float b3 = exp2f(S1[r+12] - m); S1[r+12] = b3; rs3 += b3;
    }
    float rs = (rs0 + rs1) + (rs2 + rs3);
    rs += __shfl_xor(rs, 32, 64);
    L += rs;

    // ---- P -> bf16 B-fragments via shfl_xor(32) + select ----
    s16x8 PB[4];
    #pragma unroll
    for (int t2 = 0; t2 < 2; ++t2) {
      #pragma unroll
      for (int half = 0; half < 2; ++half) {
        int bse = half*8;
        unsigned int pkA01, pkA23, pkB01, pkB23;
        if (t2 == 0) {
          pkA01 = packbf_c(S0[bse+0], S0[bse+1]);
          pkA23 = packbf_c(S0[bse+2], S0[bse+3]);
          pkB01 = packbf_c(S0[bse+4], S0[bse+5]);
          pkB23 = packbf_c(S0[bse+6], S0[bse+7]);
        } else {
          pkA01 = packbf_c(S1[bse+0], S1[bse+1]);
          pkA23 = packbf_c(S1[bse+2], S1[bse+3]);
          pkB01 = packbf_c(S1[bse+4], S1[bse+5]);
          pkB23 = packbf_c(S1[bse+6], S1[bse+7]);
        }
        unsigned int xA01 = __shfl_xor(pkA01, 32, 64);
        unsigned int xA23 = __shfl_xor(pkA23, 32, 64);
        unsigned int xB01 = __shfl_xor(pkB01, 32, 64);
        unsigned int xB23 = __shfl_xor(pkB23, 32, 64);
        union { unsigned int u[4]; s16x8 v; } f;
        f.u[0] = hi ? xB01 : pkA01;
        f.u[1] = hi ? xB23 : pkA23;
        f.u[2] = hi ? pkB01 : xA01;
        f.u[3] = hi ? pkB23 : xA23;
        PB[t2*2 + half] = f.v;
      }
    }

    // ---- O^T += V^T P^T : C[dv][q]; V^T frags from swizzled Vt[buf] ----
    const char* Vc = lds + 16384 + (tt & 1)*16384;
    __builtin_amdgcn_s_setprio(1);
    #pragma unroll
    for (int sub = 0; sub < 4; ++sub) {
      int row = sub*32 + q_;                // dv
      const char* vb2 = Vc + row*128;
      int swz = (row & 7) << 4;
      #pragma unroll
      for (int kk = 0; kk < 4; ++kk) {
        s16x8 vf = *(const s16x8*)(vb2 + ((kk*32 + hi*16) ^ swz));
        accO[sub] = __builtin_amdgcn_mfma_f32_32x32x16_bf16(vf, PB[kk], accO[sub], 0, 0, 0);
      }
    }
    __builtin_amdgcn_s_setprio(0);
  }

  // ---- epilogue: per-wave LDS bounce to coalesce [q][dv] stores ----
  __syncthreads();
  unsigned short* Ob = (unsigned short*)lds + (size_t)w*4096;   // 8KB/wave
  float inv = 1.0f / L;
  #pragma unroll
  for (int sub = 0; sub < 4; ++sub)
    #pragma unroll
    for (int j = 0; j < 8; ++j) {
      unsigned int pw = packbf_c(accO[sub][2*j]*inv, accO[sub][2*j+1]*inv);
      int dv = sub*32 + (j&1)*2 + ((j>>1)*8) + 4*hi;
      *(unsigned int*)((char*)Ob + q_*256 + ((dv*2) ^ ((q_ & 15) << 4))) = pw;
    }
  asm volatile("s_waitcnt lgkmcnt(0)" ::: "memory");
  size_t gbase = ((size_t)(b*SEQ + q0 + w*32 + q_))*D_MODEL + h*DK;
  #pragma unroll
  for (int p = 0; p < 8; ++p) {
    int chunk = hi + 2*p;
    s16x8 ov = *(const s16x8*)((char*)Ob + q_*256 + ((chunk*16) ^ ((q_ & 15) << 4)));
    *(s16x8*)(O + gbase + chunk*8) = ov;
  }
}

extern "C" void kernel_launch(void* const* d_in, const int* in_sizes, int n_in,
                              void* d_out, int out_size, void* d_ws, size_t ws_size,
                              hipStream_t stream) {
  const float* q  = (const float*)d_in[0];
  const float* k  = (const float*)d_in[1];
  const float* v  = (const float*)d_in[2];
  const float* Wq = (const float*)d_in[3];
  const float* bq = (const float*)d_in[4];
  const float* Wk = (const float*)d_in[5];
  const float* bk = (const float*)d_in[6];
  const float* Wv = (const float*)d_in[7];
  const float* bv = (const float*)d_in[8];
  const float* Wo = (const float*)d_in[9];
  const float* bo = (const float*)d_in[10];
  float* out = (float*)d_out;

  char* ws = (char*)d_ws;
  const size_t SZT = (size_t)MROWS * D_MODEL * 2;
  const size_t SZW = (size_t)D_MODEL * D_MODEL * 2;

  unsigned short* qb  = (unsigned short*)(ws);
  unsigned short* kb  = (unsigned short*)(ws + SZT);
  unsigned short* vb  = (unsigned short*)(ws + 2*SZT);
  unsigned short* WqT = (unsigned short*)(ws + 3*SZT);            // [4][2048][2048] contiguous
  unsigned short* WoT = (unsigned short*)(ws + 3*SZT + 3*SZW);
  unsigned short* Qh  = (unsigned short*)(ws + 3*SZT + 4*SZW);    // [3] tensors contiguous
  unsigned short* Kh  = (unsigned short*)(ws + 4*SZT + 4*SZW);
  unsigned short* Vh  = (unsigned short*)(ws + 5*SZT + 4*SZW);    // V^T layout [B,H,dk,S]
  unsigned short* Oc  = qb;   // qb dead after Q projection

  prep_kernel<<<dim3(12288 + 16384), 256, 0, stream>>>(q, k, v, Wq, Wk, Wv, Wo, qb, kb, vb, WqT);

  // 1/sqrt(128) * log2(e): scores computed directly in exp2 domain
  const float qscale = 0.1275174308f;
  gemm256_qkv<<<dim3(16, 16, 3), 512, 0, stream>>>(qb, kb, vb, WqT, bq, bk, bv, Qh, qscale);

  attn_kernel<<<dim3(SEQ/128, BATCH*NHEADS), 256, 0, stream>>>(Qh, Kh, Vh, Oc);

  gemm256_out<<<dim3(16, 16), 512, 0, stream>>>(Oc, WoT, bo, out);
}